// Round 9
// baseline (105.921 us; speedup 1.0000x reference)
//
#include <hip/hip_runtime.h>
#include <math.h>

#define NN    4096
#define KK    20
#define QQ    8                 // query points per lane
#define WAVES 4
#define BLK   (WAVES*64)        // 256 threads
#define PPB   (WAVES*QQ)        // 32 points per block
#define IPT   (NN/64)           // 64 j-iterations per lane per phase
#define CAP   56                // per-point candidate capacity
#define BPB   (NN/PPB)          // 128 blocks per batch
#define BB    8

__device__ __forceinline__ unsigned fkey(float f) {  // monotone float->uint
  unsigned u = __float_as_uint(f);
  return u ^ ((unsigned)((int)u >> 31) | 0x80000000u);
}
__device__ __forceinline__ float fkey_inv(unsigned k) {
  unsigned u = (k & 0x80000000u) ? (k ^ 0x80000000u) : ~k;
  return __uint_as_float(u);
}

__global__ void prep_kernel(const float* __restrict__ x, float4* __restrict__ ws4) {
  const int i = blockIdx.x * 256 + threadIdx.x;        // 32768 points
  const float* p = x + (size_t)i * 3;
  const float a = p[0], b = p[1], c = p[2];
  ws4[i] = make_float4(a, b, c, fmaf(c, c, fmaf(b, b, a * a)));
}

template<bool WS>
__global__ __launch_bounds__(BLK, 4)
void edgeconv_kernel(const float* __restrict__ x,
                     const float4* __restrict__ ws4,
                     const float* __restrict__ W,
                     const float* __restrict__ bias,
                     float* __restrict__ out) {
  __shared__ float2 cand[PPB][CAP + 1];                // 14.6 KB (d, j-bits)
  __shared__ int    jkeep[PPB][21];                    // 2.7 KB
  __shared__ int    pc[PPB];
  __shared__ int    pk[PPB];

  const int tid  = threadIdx.x;
  const int lane = tid & 63;
  const int w    = tid >> 6;
  const int bb   = blockIdx.x / BPB;
  const int blk  = blockIdx.x % BPB;
  const int base = bb * NN;
  const int g0   = w * QQ;                 // wave's first point group
  const int myp0 = blk * PPB + g0;

  // premultiplied query coeffs: d' = |xj|^2 - 2*xi.xj (order-preserving/point;
  // self value is the strict global minimum and rides along)
  float nx[QQ], ny[QQ], nz[QQ];
  #pragma unroll
  for (int q = 0; q < QQ; ++q) {
    const float* p = x + (size_t)(base + myp0 + q) * 3;
    nx[q] = -2.f * p[0]; ny[q] = -2.f * p[1]; nz[q] = -2.f * p[2];
  }

  if (tid < PPB) { pc[tid] = 0; pk[tid] = 0; }
  __syncthreads();

  // point-j loader: identical arithmetic in both paths (bit-identical d')
  auto ldp = [&](int j) -> float4 {
    if constexpr (WS) {
      return ws4[base + j];                            // coalesced dwordx4
    } else {
      const float* p = x + (size_t)(base + j) * 3;
      const float a = p[0], b = p[1], c = p[2];
      return make_float4(a, b, c, fmaf(c, c, fmaf(b, b, a * a)));
    }
  };

  // ---------------- Phase A: per-(lane,query) min over j = lane (mod 64) -----
  // No barriers: global reads are L2-resident (64 KB/batch), unroll-4 MLP.
  float m[QQ];
  #pragma unroll
  for (int q = 0; q < QQ; ++q) m[q] = INFINITY;
  #pragma unroll 4
  for (int i = 0; i < IPT; ++i) {
    const float4 v = ldp(i * 64 + lane);
    #pragma unroll
    for (int q = 0; q < QQ; ++q) {
      const float d = fmaf(nx[q], v.x, fmaf(ny[q], v.y, fmaf(nz[q], v.z, v.w)));
      m[q] = fminf(m[q], d);
    }
  }

  // ---- tau_q = exact 21st smallest of the 64 lane-minima (>= true tau;
  //      exactly one self value in the set). Ballot radix bisection. ----------
  unsigned key[QQ], lo[QQ], hi[QQ];
  #pragma unroll
  for (int q = 0; q < QQ; ++q) { key[q] = fkey(m[q]); lo[q] = 0u; hi[q] = 0xFFFFFFFFu; }
  for (int b = 0; b < 32; ++b) {
    #pragma unroll
    for (int q = 0; q < QQ; ++q) {
      const unsigned mid = lo[q] + ((hi[q] - lo[q]) >> 1);
      const unsigned long long bal = __ballot(key[q] <= mid);
      if (__popcll(bal) > KK) hi[q] = mid; else lo[q] = mid + 1;
    }
  }
  float tau[QQ];
  #pragma unroll
  for (int q = 0; q < QQ; ++q) tau[q] = fkey_inv(lo[q]);

  // ---------------- Phase B: collect candidates d' <= tau_q (self included) --
  #pragma unroll 2
  for (int i = 0; i < IPT; ++i) {
    const float4 v = ldp(i * 64 + lane);
    const int j = i * 64 + lane;
    #pragma unroll
    for (int q = 0; q < QQ; ++q) {
      const float d = fmaf(nx[q], v.x, fmaf(ny[q], v.y, fmaf(nz[q], v.z, v.w)));
      if (d <= tau[q]) {
        const int wp = atomicAdd(&pc[g0 + q], 1);
        if (wp < CAP) cand[g0 + q][wp] = make_float2(d, __int_as_float(j));
      }
    }
  }
  __syncthreads();

  // ---- Rank + compact: keep j != self with lex-rank(d, j) <= 20 (exactly 20;
  //      matches top_k's low-index tie-break; kept SET deterministic) ---------
  {
    const int g   = tid >> 3;            // 8 helper threads per point
    const int k0  = tid & 7;
    const int myp = blk * PPB + g;
    const int n0  = pc[g];
    const int n   = n0 < CAP ? n0 : CAP;
    for (int k = k0; k < n; k += 8) {
      const float2 ck = cand[g][k];
      const float dk = ck.x; const int jk = __float_as_int(ck.y);
      int rank = 0;
      for (int k2 = 0; k2 < n; ++k2) {
        const float2 c2 = cand[g][k2];
        rank += (c2.x < dk || (c2.x == dk && __float_as_int(c2.y) < jk)) ? 1 : 0;
      }
      if (jk != myp && rank <= KK) jkeep[g][atomicAdd(&pk[g], 1)] = jk;
    }
  }
  __syncthreads();

  // ---------------- Feature phase: lane = channel; h = xj.w345 + const_i -----
  const float w3 = W[3*64+lane], w4 = W[4*64+lane], w5 = W[5*64+lane];
  const float c0 = W[0*64+lane] - w3;
  const float c1 = W[1*64+lane] - w4;
  const float c2 = W[2*64+lane] - w5;
  const float bo = bias[lane];

  for (int pi = 0; pi < QQ; ++pi) {          // wave's own 8 points
    const int p   = g0 + pi;
    const int pid = blk * PPB + p;
    const float* xi = x + (size_t)(base + pid) * 3;
    const float ci = fmaf(xi[0], c0, fmaf(xi[1], c1, fmaf(xi[2], c2, bo)));
    float hmax = -INFINITY;
    #pragma unroll 5
    for (int k = 0; k < KK; ++k) {           // exactly 20, wave-uniform
      const int j = jkeep[p][k];
      const float* xp = x + (size_t)(base + j) * 3;
      hmax = fmaxf(hmax, fmaf(xp[0], w3, fmaf(xp[1], w4, fmaf(xp[2], w5, ci))));
    }
    out[(size_t)(base + pid) * 64 + lane] = fmaxf(hmax, 0.0f);
  }
}

extern "C" void kernel_launch(void* const* d_in, const int* in_sizes, int n_in,
                              void* d_out, int out_size, void* d_ws, size_t ws_size,
                              hipStream_t stream) {
  const float* x  = (const float*)d_in[0];
  // d_in[1] = batch (implicit: i / N) — unused
  const float* W  = (const float*)d_in[2];
  const float* b  = (const float*)d_in[3];
  float* out = (float*)d_out;

  const size_t need = (size_t)BB * NN * sizeof(float4);   // 512 KB
  dim3 grid(BB * BPB);   // 1024 blocks
  dim3 block(BLK);
  if (ws_size >= need) {
    float4* ws4 = (float4*)d_ws;
    hipLaunchKernelGGL(prep_kernel, dim3(BB * NN / 256), dim3(256), 0, stream, x, ws4);
    hipLaunchKernelGGL((edgeconv_kernel<true>), grid, block, 0, stream, x, ws4, W, b, out);
  } else {
    hipLaunchKernelGGL((edgeconv_kernel<false>), grid, block, 0, stream,
                       x, (const float4*)nullptr, W, b, out);
  }
}

// Round 10
// 96.194 us; speedup vs baseline: 1.1011x; 1.1011x over previous
//
#include <hip/hip_runtime.h>
#include <math.h>

#define NN    4096
#define KK    20
#define QQ    4                 // query points per lane (per wave)
#define WAVES 4
#define BLK   (WAVES*64)        // 256 threads
#define PPB   (WAVES*QQ)        // 16 points per block
#define IPT   (NN/64)           // 64 j-iterations per lane per phase
#define CAP   56                // per-point candidate capacity
#define BPB   (NN/PPB)          // 256 blocks per batch
#define BB    8

__device__ __forceinline__ unsigned fkey(float f) {  // monotone float->uint
  unsigned u = __float_as_uint(f);
  return u ^ ((unsigned)((int)u >> 31) | 0x80000000u);
}
__device__ __forceinline__ float fkey_inv(unsigned k) {
  unsigned u = (k & 0x80000000u) ? (k ^ 0x80000000u) : ~k;
  return __uint_as_float(u);
}

__global__ void prep_kernel(const float* __restrict__ x, float4* __restrict__ ws4) {
  const int i = blockIdx.x * 256 + threadIdx.x;        // 32768 points
  const float* p = x + (size_t)i * 3;
  const float a = p[0], b = p[1], c = p[2];
  ws4[i] = make_float4(a, b, c, fmaf(c, c, fmaf(b, b, a * a)));
}

template<bool WS>
__global__ __launch_bounds__(BLK, 8)
void edgeconv_kernel(const float* __restrict__ x,
                     const float4* __restrict__ ws4,
                     const float* __restrict__ W,
                     const float* __restrict__ bias,
                     float* __restrict__ out) {
  __shared__ float2 cand[PPB][CAP + 1];                // 7.3 KB (d, j-bits)
  __shared__ int    jkeep[PPB][21];                    // 1.3 KB
  __shared__ int    pc[PPB];
  __shared__ int    pk[PPB];

  const int tid  = threadIdx.x;
  const int lane = tid & 63;
  const int w    = tid >> 6;
  const int bb   = blockIdx.x / BPB;
  const int blk  = blockIdx.x % BPB;
  const int base = bb * NN;
  const int g0   = w * QQ;                 // wave's first point group
  const int myp0 = blk * PPB + g0;

  // premultiplied query coeffs: d' = |xj|^2 - 2*xi.xj (order-preserving/point;
  // self value is the strict global minimum and rides along)
  float nx[QQ], ny[QQ], nz[QQ];
  #pragma unroll
  for (int q = 0; q < QQ; ++q) {
    const float* p = x + (size_t)(base + myp0 + q) * 3;
    nx[q] = -2.f * p[0]; ny[q] = -2.f * p[1]; nz[q] = -2.f * p[2];
  }

  if (tid < PPB) { pc[tid] = 0; pk[tid] = 0; }
  __syncthreads();

  // point-j loader: identical arithmetic in both paths (bit-identical d')
  auto ldp = [&](int j) -> float4 {
    if constexpr (WS) {
      return ws4[base + j];                            // coalesced dwordx4
    } else {
      const float* p = x + (size_t)(base + j) * 3;
      const float a = p[0], b = p[1], c = p[2];
      return make_float4(a, b, c, fmaf(c, c, fmaf(b, b, a * a)));
    }
  };

  // ---------------- Phase A: per-(lane,query) min over j = lane (mod 64) -----
  // No barriers; register-rotated prefetch keeps >=1 load in flight.
  float m[QQ];
  #pragma unroll
  for (int q = 0; q < QQ; ++q) m[q] = INFINITY;
  {
    float4 v = ldp(lane);
    #pragma unroll 8
    for (int i = 0; i < IPT; ++i) {
      float4 vn;
      if (i + 1 < IPT) vn = ldp((i + 1) * 64 + lane);
      #pragma unroll
      for (int q = 0; q < QQ; ++q) {
        const float d = fmaf(nx[q], v.x, fmaf(ny[q], v.y, fmaf(nz[q], v.z, v.w)));
        m[q] = fminf(m[q], d);
      }
      v = vn;
    }
  }

  // ---- tau_q = exact 21st smallest of the 64 lane-minima (>= true tau;
  //      exactly one self value in the set). Ballot radix bisection. ----------
  unsigned key[QQ], lo[QQ], hi[QQ];
  #pragma unroll
  for (int q = 0; q < QQ; ++q) { key[q] = fkey(m[q]); lo[q] = 0u; hi[q] = 0xFFFFFFFFu; }
  for (int b = 0; b < 32; ++b) {
    #pragma unroll
    for (int q = 0; q < QQ; ++q) {
      const unsigned mid = lo[q] + ((hi[q] - lo[q]) >> 1);
      const unsigned long long bal = __ballot(key[q] <= mid);
      if (__popcll(bal) > KK) hi[q] = mid; else lo[q] = mid + 1;
    }
  }
  float tau[QQ];
  #pragma unroll
  for (int q = 0; q < QQ; ++q) tau[q] = fkey_inv(lo[q]);

  // ---------------- Phase B: collect candidates d' <= tau_q (self included) --
  {
    float4 v = ldp(lane);
    #pragma unroll 4
    for (int i = 0; i < IPT; ++i) {
      float4 vn;
      if (i + 1 < IPT) vn = ldp((i + 1) * 64 + lane);
      const int j = i * 64 + lane;
      #pragma unroll
      for (int q = 0; q < QQ; ++q) {
        const float d = fmaf(nx[q], v.x, fmaf(ny[q], v.y, fmaf(nz[q], v.z, v.w)));
        if (d <= tau[q]) {
          const int wp = atomicAdd(&pc[g0 + q], 1);
          if (wp < CAP) cand[g0 + q][wp] = make_float2(d, __int_as_float(j));
        }
      }
      v = vn;
    }
  }
  __syncthreads();

  // ---- Rank + compact: keep j != self with lex-rank(d, j) <= 20 (exactly 20;
  //      matches top_k's low-index tie-break; kept SET deterministic) ---------
  {
    const int g   = tid >> 4;            // 16 helper threads per point
    const int k0  = tid & 15;
    const int myp = blk * PPB + g;
    const int n0  = pc[g];
    const int n   = n0 < CAP ? n0 : CAP;
    for (int k = k0; k < n; k += 16) {
      const float2 ck = cand[g][k];
      const float dk = ck.x; const int jk = __float_as_int(ck.y);
      int rank = 0;
      for (int k2 = 0; k2 < n; ++k2) {
        const float2 c2 = cand[g][k2];
        rank += (c2.x < dk || (c2.x == dk && __float_as_int(c2.y) < jk)) ? 1 : 0;
      }
      if (jk != myp && rank <= KK) jkeep[g][atomicAdd(&pk[g], 1)] = jk;
    }
  }
  __syncthreads();

  // ---------------- Feature phase: lane = channel; h = xj.w345 + const_i -----
  const float w3 = W[3*64+lane], w4 = W[4*64+lane], w5 = W[5*64+lane];
  const float c0 = W[0*64+lane] - w3;
  const float c1 = W[1*64+lane] - w4;
  const float c2 = W[2*64+lane] - w5;
  const float bo = bias[lane];

  for (int pi = 0; pi < QQ; ++pi) {          // wave's own 4 points
    const int p   = g0 + pi;
    const int pid = blk * PPB + p;
    const float* xi = x + (size_t)(base + pid) * 3;
    const float ci = fmaf(xi[0], c0, fmaf(xi[1], c1, fmaf(xi[2], c2, bo)));
    float hmax = -INFINITY;
    #pragma unroll 5
    for (int k = 0; k < KK; ++k) {           // exactly 20, wave-uniform
      const int j = jkeep[p][k];
      const float* xp = x + (size_t)(base + j) * 3;
      hmax = fmaxf(hmax, fmaf(xp[0], w3, fmaf(xp[1], w4, fmaf(xp[2], w5, ci))));
    }
    out[(size_t)(base + pid) * 64 + lane] = fmaxf(hmax, 0.0f);
  }
}

extern "C" void kernel_launch(void* const* d_in, const int* in_sizes, int n_in,
                              void* d_out, int out_size, void* d_ws, size_t ws_size,
                              hipStream_t stream) {
  const float* x  = (const float*)d_in[0];
  // d_in[1] = batch (implicit: i / N) — unused
  const float* W  = (const float*)d_in[2];
  const float* b  = (const float*)d_in[3];
  float* out = (float*)d_out;

  const size_t need = (size_t)BB * NN * sizeof(float4);   // 512 KB
  dim3 grid(BB * BPB);   // 2048 blocks: 8 blocks/CU exactly
  dim3 block(BLK);
  if (ws_size >= need) {
    float4* ws4 = (float4*)d_ws;
    hipLaunchKernelGGL(prep_kernel, dim3(BB * NN / 256), dim3(256), 0, stream, x, ws4);
    hipLaunchKernelGGL((edgeconv_kernel<true>), grid, block, 0, stream, x, ws4, W, b, out);
  } else {
    hipLaunchKernelGGL((edgeconv_kernel<false>), grid, block, 0, stream,
                       x, (const float4*)nullptr, W, b, out);
  }
}

// Round 12
// 85.109 us; speedup vs baseline: 1.2445x; 1.1302x over previous
//
#include <hip/hip_runtime.h>
#include <math.h>

#define NN    4096
#define KK    20
#define QQ    4                 // query points per lane (per wave)
#define WAVES 4
#define BLK   (WAVES*64)        // 256 threads
#define PPB   (WAVES*QQ)        // 16 points per block
#define IPT   (NN/64)           // 64 j-iterations per lane per phase
#define CAP   56                // per-point candidate capacity
#define BPB   (NN/PPB)          // 256 blocks per batch
#define BB    8

__device__ __forceinline__ unsigned fkey(float f) {  // monotone float->uint
  unsigned u = __float_as_uint(f);
  return u ^ ((unsigned)((int)u >> 31) | 0x80000000u);
}
__device__ __forceinline__ float fkey_inv(unsigned k) {
  unsigned u = (k & 0x80000000u) ? (k ^ 0x80000000u) : ~k;
  return __uint_as_float(u);
}

__global__ void prep_kernel(const float* __restrict__ x, float4* __restrict__ ws4) {
  const int i = blockIdx.x * 256 + threadIdx.x;        // 32768 points
  const float* p = x + (size_t)i * 3;
  const float a = p[0], b = p[1], c = p[2];
  ws4[i] = make_float4(a, b, c, fmaf(c, c, fmaf(b, b, a * a)));
}

template<bool WS>
__global__ __launch_bounds__(BLK, 8)
void edgeconv_kernel(const float* __restrict__ x,
                     const float4* __restrict__ ws4,
                     const float* __restrict__ W,
                     const float* __restrict__ bias,
                     float* __restrict__ out) {
  __shared__ float2 cand[PPB][CAP + 1];                // 7.3 KB (d, j-bits)
  __shared__ int    jkeep[PPB][21];                    // 1.3 KB
  __shared__ int    pc[PPB];
  __shared__ int    pk[PPB];

  const int tid  = threadIdx.x;
  const int lane = tid & 63;
  const int w    = tid >> 6;
  const int bb   = blockIdx.x / BPB;
  const int blk  = blockIdx.x % BPB;
  const int base = bb * NN;
  const int g0   = w * QQ;                 // wave's first point group
  const int myp0 = blk * PPB + g0;

  // premultiplied query coeffs: d' = |xj|^2 - 2*xi.xj (order-preserving/point;
  // self value is the strict global minimum and rides along)
  float nx[QQ], ny[QQ], nz[QQ];
  #pragma unroll
  for (int q = 0; q < QQ; ++q) {
    const float* p = x + (size_t)(base + myp0 + q) * 3;
    nx[q] = -2.f * p[0]; ny[q] = -2.f * p[1]; nz[q] = -2.f * p[2];
  }

  if (tid < PPB) { pc[tid] = 0; pk[tid] = 0; }
  __syncthreads();

  // point-j loader: identical arithmetic in both paths (bit-identical d')
  auto ldp = [&](int j) -> float4 {
    if constexpr (WS) {
      return ws4[base + j];                            // coalesced dwordx4
    } else {
      const float* p = x + (size_t)(base + j) * 3;
      const float a = p[0], b = p[1], c = p[2];
      return make_float4(a, b, c, fmaf(c, c, fmaf(b, b, a * a)));
    }
  };

  // ---------------- Phase A: per-(lane,query) min over j = lane (mod 64) -----
  // 4-wide load batches, unroll 1: <=16 load regs in flight; TLP hides L2.
  float m[QQ];
  #pragma unroll
  for (int q = 0; q < QQ; ++q) m[q] = INFINITY;
  #pragma unroll 1
  for (int i = 0; i < IPT; i += 4) {
    const float4 v0 = ldp((i + 0) * 64 + lane);
    const float4 v1 = ldp((i + 1) * 64 + lane);
    const float4 v2 = ldp((i + 2) * 64 + lane);
    const float4 v3 = ldp((i + 3) * 64 + lane);
    #pragma unroll
    for (int q = 0; q < QQ; ++q) {
      const float d0 = fmaf(nx[q], v0.x, fmaf(ny[q], v0.y, fmaf(nz[q], v0.z, v0.w)));
      const float d1 = fmaf(nx[q], v1.x, fmaf(ny[q], v1.y, fmaf(nz[q], v1.z, v1.w)));
      const float d2 = fmaf(nx[q], v2.x, fmaf(ny[q], v2.y, fmaf(nz[q], v2.z, v2.w)));
      const float d3 = fmaf(nx[q], v3.x, fmaf(ny[q], v3.y, fmaf(nz[q], v3.z, v3.w)));
      m[q] = fminf(fminf(fminf(fminf(m[q], d0), d1), d2), d3);  // -> v_min3
    }
  }

  // ---- tau_q = exact 21st smallest of the 64 lane-minima (>= true tau;
  //      exactly one self value in the set). Ballot radix bisection,
  //      sequential per q to minimize live registers. -----------------------
  float tau[QQ];
  #pragma unroll
  for (int q = 0; q < QQ; ++q) {
    const unsigned key = fkey(m[q]);
    unsigned lo = 0u, hi = 0xFFFFFFFFu;
    for (int b = 0; b < 32; ++b) {
      const unsigned mid = lo + ((hi - lo) >> 1);
      const unsigned long long bal = __ballot(key <= mid);
      if (__popcll(bal) > KK) hi = mid; else lo = mid + 1;
    }
    tau[q] = fkey_inv(lo);
  }

  // ---------------- Phase B: collect candidates d' <= tau_q (self included) --
  #pragma unroll 1
  for (int i = 0; i < IPT; i += 4) {
    const float4 v0 = ldp((i + 0) * 64 + lane);
    const float4 v1 = ldp((i + 1) * 64 + lane);
    const float4 v2 = ldp((i + 2) * 64 + lane);
    const float4 v3 = ldp((i + 3) * 64 + lane);
    #pragma unroll
    for (int q = 0; q < QQ; ++q) {
      const float d0 = fmaf(nx[q], v0.x, fmaf(ny[q], v0.y, fmaf(nz[q], v0.z, v0.w)));
      const float d1 = fmaf(nx[q], v1.x, fmaf(ny[q], v1.y, fmaf(nz[q], v1.z, v1.w)));
      const float d2 = fmaf(nx[q], v2.x, fmaf(ny[q], v2.y, fmaf(nz[q], v2.z, v2.w)));
      const float d3 = fmaf(nx[q], v3.x, fmaf(ny[q], v3.y, fmaf(nz[q], v3.z, v3.w)));
      if (d0 <= tau[q]) { const int wp = atomicAdd(&pc[g0 + q], 1);
        if (wp < CAP) cand[g0 + q][wp] = make_float2(d0, __int_as_float((i + 0) * 64 + lane)); }
      if (d1 <= tau[q]) { const int wp = atomicAdd(&pc[g0 + q], 1);
        if (wp < CAP) cand[g0 + q][wp] = make_float2(d1, __int_as_float((i + 1) * 64 + lane)); }
      if (d2 <= tau[q]) { const int wp = atomicAdd(&pc[g0 + q], 1);
        if (wp < CAP) cand[g0 + q][wp] = make_float2(d2, __int_as_float((i + 2) * 64 + lane)); }
      if (d3 <= tau[q]) { const int wp = atomicAdd(&pc[g0 + q], 1);
        if (wp < CAP) cand[g0 + q][wp] = make_float2(d3, __int_as_float((i + 3) * 64 + lane)); }
    }
  }
  __syncthreads();

  // ---- Rank + compact: keep j != self with lex-rank(d, j) <= 20 (exactly 20;
  //      matches top_k's low-index tie-break; kept SET deterministic) ---------
  {
    const int g   = tid >> 4;            // 16 helper threads per point
    const int k0  = tid & 15;
    const int myp = blk * PPB + g;
    const int n0  = pc[g];
    const int n   = n0 < CAP ? n0 : CAP;
    for (int k = k0; k < n; k += 16) {
      const float2 ck = cand[g][k];
      const float dk = ck.x; const int jk = __float_as_int(ck.y);
      int rank = 0;
      for (int k2 = 0; k2 < n; ++k2) {
        const float2 c2 = cand[g][k2];
        rank += (c2.x < dk || (c2.x == dk && __float_as_int(c2.y) < jk)) ? 1 : 0;
      }
      if (jk != myp && rank <= KK) jkeep[g][atomicAdd(&pk[g], 1)] = jk;
    }
  }
  __syncthreads();

  // ---------------- Feature phase: lane = channel; h = xj.w345 + const_i -----
  const float w3 = W[3*64+lane], w4 = W[4*64+lane], w5 = W[5*64+lane];
  const float c0 = W[0*64+lane] - w3;
  const float c1 = W[1*64+lane] - w4;
  const float c2 = W[2*64+lane] - w5;
  const float bo = bias[lane];

  for (int pi = 0; pi < QQ; ++pi) {          // wave's own 4 points
    const int p   = g0 + pi;
    const int pid = blk * PPB + p;
    const float4 xi = ldp(pid);              // query point (plain index!)
    const float ci = fmaf(xi.x, c0, fmaf(xi.y, c1, fmaf(xi.z, c2, bo)));
    float hmax = -INFINITY;
    #pragma unroll 5
    for (int k = 0; k < KK; ++k) {           // exactly 20, wave-uniform
      const int j = jkeep[p][k];
      const float4 xp = ldp(j);              // 1 dwordx4 (WS) vs 3 dwords
      hmax = fmaxf(hmax, fmaf(xp.x, w3, fmaf(xp.y, w4, fmaf(xp.z, w5, ci))));
    }
    out[(size_t)(base + pid) * 64 + lane] = fmaxf(hmax, 0.0f);
  }
}

extern "C" void kernel_launch(void* const* d_in, const int* in_sizes, int n_in,
                              void* d_out, int out_size, void* d_ws, size_t ws_size,
                              hipStream_t stream) {
  const float* x  = (const float*)d_in[0];
  // d_in[1] = batch (implicit: i / N) — unused
  const float* W  = (const float*)d_in[2];
  const float* b  = (const float*)d_in[3];
  float* out = (float*)d_out;

  const size_t need = (size_t)BB * NN * sizeof(float4);   // 512 KB
  dim3 grid(BB * BPB);   // 2048 blocks: 8 blocks/CU exactly
  dim3 block(BLK);
  if (ws_size >= need) {
    float4* ws4 = (float4*)d_ws;
    hipLaunchKernelGGL(prep_kernel, dim3(BB * NN / 256), dim3(256), 0, stream, x, ws4);
    hipLaunchKernelGGL((edgeconv_kernel<true>), grid, block, 0, stream, x, ws4, W, b, out);
  } else {
    hipLaunchKernelGGL((edgeconv_kernel<false>), grid, block, 0, stream,
                       x, (const float4*)nullptr, W, b, out);
  }
}